// Round 4
// baseline (69.268 us; speedup 1.0000x reference)
//
#include <hip/hip_runtime.h>

// loss = || F^T F - S^T S ||_F^2 / 2^38
// F = input.reshape(64, 8192).T, S = target.reshape(64, 8192).T
// Exact rewrite of sum((FF^T+c)^d + (SS^T+c)^d - 2(FS^T+c)^d) for c=0, d=2.

#define CH    64
#define KTOT  8192
#define G1    256            // gram blocks
#define KPB   32             // k per block
#define KPW   8              // k per wave (4 waves/block)
#define NPART 2              // partials written per block
#define NP    (G1 * NPART)   // 512 total partials

// 1 / (8192 * 8192 * 64 * 64) = 2^-38
#define NORMF 3.637978807091713e-12f

// Swizzled column for the cross-wave reduce buffer. Naive [row][col] has an
// 8-way bank conflict (8 ta-groups at 256 B stride land on one bank);
// tb^ta is a Latin square over {0,8,...,56} -> 2-way (free), float4-aligned.
#define RCOL(row, tb) ((tb) ^ ((row) & 56))

__global__ __launch_bounds__(256, 1) void gram_partial(
    const float* __restrict__ in, const float* __restrict__ tg,
    float* __restrict__ ws, float* __restrict__ out)
{
    // Transposed tiles [k][ch]: compute reads contiguous float4 along ch.
    __shared__ __attribute__((aligned(16))) float ts_in[KPB][CH];   // 8 KiB
    __shared__ __attribute__((aligned(16))) float ts_tg[KPB][CH];   // 8 KiB
    __shared__ __attribute__((aligned(16))) float red[2][CH][CH];   // 32 KiB

    const int t  = threadIdx.x;
    const int k0 = blockIdx.x * KPB;

    // zero the scalar accumulator (kernel boundary orders this before
    // reduce_square's atomics)
    if (blockIdx.x == 0 && t == 0) out[0] = 0.f;

    // --- stage, transpose-on-write. 8 consecutive lanes cover one row's
    // 128 B contiguously (good global coalescing); 2 rounds of 64 ch rows.
    {
        const int lk = (t & 7) << 2;         // 0,4,...,28
#pragma unroll
        for (int r = 0; r < 2; ++r) {
            const int lch = (t >> 3) + 32 * r;   // 0..63
            const float4 vi = *(const float4*)(in + lch * KTOT + k0 + lk);
            const float4 vt = *(const float4*)(tg + lch * KTOT + k0 + lk);
            ts_in[lk + 0][lch] = vi.x; ts_in[lk + 1][lch] = vi.y;
            ts_in[lk + 2][lch] = vi.z; ts_in[lk + 3][lch] = vi.w;
            ts_tg[lk + 0][lch] = vt.x; ts_tg[lk + 1][lch] = vt.y;
            ts_tg[lk + 2][lch] = vt.z; ts_tg[lk + 3][lch] = vt.w;
        }
    }
    __syncthreads();

    // --- compute: wave w owns kk in [w*8, w*8+8); each lane an 8x8 tile.
    const int w    = t >> 6;             // 0..3
    const int lane = t & 63;
    const int ta   = (lane >> 3) << 3;   // 0,8,...,56
    const int tb   = (lane & 7) << 3;    // 0,8,...,56

    float acc[8][8];
#pragma unroll
    for (int i = 0; i < 8; ++i)
#pragma unroll
        for (int j = 0; j < 8; ++j) acc[i][j] = 0.f;

#pragma unroll
    for (int kk = w * KPW; kk < w * KPW + KPW; ++kk) {
        const float4 x0 = *(const float4*)&ts_in[kk][ta];
        const float4 x1 = *(const float4*)&ts_in[kk][ta + 4];
        const float4 y0 = *(const float4*)&ts_in[kk][tb];
        const float4 y1 = *(const float4*)&ts_in[kk][tb + 4];
        const float4 u0 = *(const float4*)&ts_tg[kk][ta];
        const float4 u1 = *(const float4*)&ts_tg[kk][ta + 4];
        const float4 v0 = *(const float4*)&ts_tg[kk][tb];
        const float4 v1 = *(const float4*)&ts_tg[kk][tb + 4];
        const float A[8] = {x0.x, x0.y, x0.z, x0.w, x1.x, x1.y, x1.z, x1.w};
        const float B[8] = {y0.x, y0.y, y0.z, y0.w, y1.x, y1.y, y1.z, y1.w};
        const float C[8] = {u0.x, u0.y, u0.z, u0.w, u1.x, u1.y, u1.z, u1.w};
        const float D[8] = {v0.x, v0.y, v0.z, v0.w, v1.x, v1.y, v1.z, v1.w};
#pragma unroll
        for (int i = 0; i < 8; ++i)
#pragma unroll
            for (int j = 0; j < 8; ++j) {
                acc[i][j] = fmaf(A[i], B[j], acc[i][j]);
                acc[i][j] = fmaf(-C[i], D[j], acc[i][j]);
            }
    }

    // --- pairwise cross-wave reduce: waves 2,3 -> LDS; waves 0,1 add and
    // write NPART=2 partials per block.
    if (w >= 2) {
#pragma unroll
        for (int i = 0; i < 8; ++i) {
            const int row = ta + i;
            const int cc  = RCOL(row, tb);
            float4 a, b;
            a.x = acc[i][0]; a.y = acc[i][1]; a.z = acc[i][2]; a.w = acc[i][3];
            b.x = acc[i][4]; b.y = acc[i][5]; b.z = acc[i][6]; b.w = acc[i][7];
            *(float4*)&red[w - 2][row][cc]     = a;
            *(float4*)&red[w - 2][row][cc + 4] = b;
        }
    }
    __syncthreads();
    if (w < 2) {
        float* p = ws + (blockIdx.x * NPART + w) * 4096;
#pragma unroll
        for (int i = 0; i < 8; ++i) {
            const int row = ta + i;
            const int cc  = RCOL(row, tb);
            const float4 r0 = *(const float4*)&red[w][row][cc];
            const float4 r1 = *(const float4*)&red[w][row][cc + 4];
            float4 a, b;
            a.x = acc[i][0] + r0.x; a.y = acc[i][1] + r0.y;
            a.z = acc[i][2] + r0.z; a.w = acc[i][3] + r0.w;
            b.x = acc[i][4] + r1.x; b.y = acc[i][5] + r1.y;
            b.z = acc[i][6] + r1.z; b.w = acc[i][7] + r1.w;
            *(float4*)(p + row * 64 + tb)     = a;
            *(float4*)(p + row * 64 + tb + 4) = b;
        }
    }
}

__global__ __launch_bounds__(256) void reduce_square(
    const float* __restrict__ ws, float* __restrict__ out)
{
    // 256 blocks x 16 entries; 16 slices of 32 partials per entry.
    __shared__ float red2[16][16];
    const int t  = threadIdx.x;
    const int el = t & 15;                     // entry within block
    const int sl = t >> 4;                     // 0..15
    const int e  = (blockIdx.x << 4) + el;     // gram entry 0..4095

    float s = 0.f;
    const int p0 = sl * (NP / 16);
#pragma unroll
    for (int p = p0; p < p0 + (NP / 16); ++p)  // 32 independent loads
        s += ws[p * 4096 + e];
    red2[sl][el] = s;
    __syncthreads();

    if (t < 64) {                              // wave 0 only
        float sq = 0.f;
        if (t < 16) {
            float tot = 0.f;
#pragma unroll
            for (int i = 0; i < 16; ++i) tot += red2[i][t];
            sq = tot * tot;
        }
        // lanes 16..63 carry 0, so the 16-wide tree sums lanes 0..15
#pragma unroll
        for (int off = 8; off > 0; off >>= 1)
            sq += __shfl_down(sq, off);
        if (t == 0) atomicAdd(out, sq * NORMF);
    }
}

extern "C" void kernel_launch(void* const* d_in, const int* in_sizes, int n_in,
                              void* d_out, int out_size, void* d_ws, size_t ws_size,
                              hipStream_t stream)
{
    const float* in = (const float*)d_in[0];
    const float* tg = (const float*)d_in[1];
    float* out = (float*)d_out;
    float* ws  = (float*)d_ws;   // uses NP*4096*4 = 8 MiB

    gram_partial<<<G1, 256, 0, stream>>>(in, tg, ws, out);
    reduce_square<<<256, 256, 0, stream>>>(ws, out);
}